// Round 6
// baseline (99.959 us; speedup 1.0000x reference)
//
#include <hip/hip_runtime.h>
#include <hip/hip_bf16.h>

// Pipeline (chain = b*768 + c1, 12288 chains; pos in [0,1156)):
//  d_ws  : xt [12288][1156] fp32 = 56.8 MB. GEMM writes INTERIOR positions only;
//          border positions are never materialized (scan synthesizes bias[c1]).
//  d_out : scratch for bf16 A ([16384][768]) + bf16 W ([768][768]) during GEMM,
//          then fully overwritten with the final cropped output by scan_emit_k.
//  1) prep_k         : convert_x + convert_w (bf16)
//  2) conv_gemm_mfma : 128x128 MFMA bf16 GEMM (+bias), 2-phase LDS dbuf,
//                      swapped-operand MFMA for coalesced epilogue,
//                      2-bit source-XOR LDS swizzle (8-way -> 4-way conflicts)
//  3) scan_emit_k    : wave-parallel recurrence (32 lanes/chain, 3-step
//                      Hillis-Steele, 4-row register prefetch), border synth,
//                      fused crop emit.

typedef __attribute__((ext_vector_type(8))) short s8v;     // 8 bf16
typedef __attribute__((ext_vector_type(4))) float f4v;     // MFMA acc
typedef __attribute__((ext_vector_type(8))) unsigned short us8;

__device__ __forceinline__ unsigned short f2bf(float f) {
    __hip_bfloat16 h = __float2bfloat16(f);
    return *reinterpret_cast<unsigned short*>(&h);
}

__device__ __forceinline__ void gload_lds16(const void* g, void* l) {
    __builtin_amdgcn_global_load_lds(
        (const __attribute__((address_space(1))) unsigned int*)g,
        (__attribute__((address_space(3))) unsigned int*)l,
        16, 0, 0);
}

// block ranges: [0,6144) convert_x, [6144,6432) convert_w
__global__ __launch_bounds__(256) void prep_k(const float* __restrict__ x,
                                              const float* __restrict__ w,
                                              unsigned short* __restrict__ a_bf,
                                              unsigned short* __restrict__ w_bf) {
    const int bid = blockIdx.x;
    if (bid < 6144) {
        // x [16][3][512][512] f32 -> A_bf [16384][768] bf16, m=(b,ph,pw), k=(c,py,px)
        int g = bid * 256 + threadIdx.x;
        int f = g << 3;
        int wc = f & 511;
        int h  = (f >> 9) & 511;
        int cb = f >> 18;
        int c  = cb % 3, b = cb / 3;
        const float4 v0 = *(const float4*)(x + f);
        const float4 v1 = *(const float4*)(x + f + 4);
        int m = (b << 10) + ((h >> 4) << 5) + (wc >> 4);
        int k = (c << 8) + ((h & 15) << 4) + (wc & 15);
        us8 o;
        o[0] = f2bf(v0.x); o[1] = f2bf(v0.y); o[2] = f2bf(v0.z); o[3] = f2bf(v0.w);
        o[4] = f2bf(v1.x); o[5] = f2bf(v1.y); o[6] = f2bf(v1.z); o[7] = f2bf(v1.w);
        *(us8*)(a_bf + (size_t)m * 768 + k) = o;
    } else {
        int g = (bid - 6144) * 256 + threadIdx.x;
        int f = g << 3;
        const float4 v0 = *(const float4*)(w + f);
        const float4 v1 = *(const float4*)(w + f + 4);
        us8 u;
        u[0] = f2bf(v0.x); u[1] = f2bf(v0.y); u[2] = f2bf(v0.z); u[3] = f2bf(v0.w);
        u[4] = f2bf(v1.x); u[5] = f2bf(v1.y); u[6] = f2bf(v1.z); u[7] = f2bf(v1.w);
        *(us8*)(w_bf + f) = u;
    }
}

// C[m][n] = sum_k A[m][k] * W[n][k]; 128x128 tile, BK=32, 4 waves, 2-phase dbuf.
// MFMA called as mfma(b, a): D row = n-part, D col (lane&15) = m-part ->
// epilogue stores hit 16 consecutive pos per 16-lane segment (64B coalesced).
__global__ __launch_bounds__(256) void conv_gemm_mfma_k(const unsigned short* __restrict__ A,
                                                        const unsigned short* __restrict__ W,
                                                        const float* __restrict__ bias,
                                                        float* __restrict__ xt) {
    __shared__ __align__(16) unsigned short As[2][128 * 32];
    __shared__ __align__(16) unsigned short Bs[2][128 * 32];
    const int tid  = threadIdx.x;
    const int lane = tid & 63, wv = tid >> 6;
    const int wr = wv >> 1, wc = wv & 1;
    const int m0 = blockIdx.x << 7, n0 = blockIdx.y << 7;

    f4v acc[4][4] = {};

    // staging with 2-bit source-XOR swizzle: LDS[row][chunk] holds global
    // chunk (chunk ^ (row&3)); reads apply the same XOR (involution).
    const int l2 = lane >> 2;
    const int kx = ((lane & 3) ^ (l2 & 3)) << 3;
    const unsigned short* gA = A + (size_t)(m0 + (wv << 5) + l2) * 768 + kx;
    const unsigned short* gB = W + (size_t)(n0 + (wv << 5) + l2) * 768 + kx;

    auto stage = [&](int buf, int k0) {
        gload_lds16(gA + k0,            As[buf] + (wv << 10));
        gload_lds16(gA + k0 + 16 * 768, As[buf] + (wv << 10) + 512);
        gload_lds16(gB + k0,            Bs[buf] + (wv << 10));
        gload_lds16(gB + k0 + 16 * 768, Bs[buf] + (wv << 10) + 512);
    };

    stage(0, 0);
    asm volatile("s_waitcnt vmcnt(0)" ::: "memory");
    __syncthreads();

    int cur = 0;
    for (int t = 0; t < 24; ++t) {
        if (t < 23) stage(cur ^ 1, (t + 1) << 5);      // prefetch next K-tile
        s8v a[4], b[4];
        #pragma unroll
        for (int mi = 0; mi < 4; ++mi) {
            int ra = (wr << 6) + (mi << 4) + (lane & 15);
            a[mi] = *(const s8v*)(As[cur] + (ra << 5) + (((lane >> 4) ^ (ra & 3)) << 3));
        }
        #pragma unroll
        for (int ni = 0; ni < 4; ++ni) {
            int rb = (wc << 6) + (ni << 4) + (lane & 15);
            b[ni] = *(const s8v*)(Bs[cur] + (rb << 5) + (((lane >> 4) ^ (rb & 3)) << 3));
        }
        #pragma unroll
        for (int mi = 0; mi < 4; ++mi)
            #pragma unroll
            for (int ni = 0; ni < 4; ++ni)
                acc[mi][ni] = __builtin_amdgcn_mfma_f32_16x16x32_bf16(b[ni], a[mi], acc[mi][ni], 0, 0, 0);
        asm volatile("s_waitcnt vmcnt(0)" ::: "memory");
        __syncthreads();
        cur ^= 1;
    }

    // bias for the 16 n-values this lane owns (4 per ni, r-contiguous)
    float4 bv4[4];
    #pragma unroll
    for (int ni = 0; ni < 4; ++ni)
        bv4[ni] = *(const float4*)(bias + n0 + (wc << 6) + (ni << 4) + ((lane >> 4) << 2));

    #pragma unroll
    for (int mi = 0; mi < 4; ++mi) {
        int m  = m0 + (wr << 6) + (mi << 4) + (lane & 15);
        int bb = m >> 10, ph = (m >> 5) & 31, pw = m & 31;
        int pos = (ph + 1) * 34 + (pw + 1);
        size_t base = (size_t)bb * 768;
        #pragma unroll
        for (int ni = 0; ni < 4; ++ni) {
            int n = n0 + (wc << 6) + (ni << 4) + ((lane >> 4) << 2);
            const float* bp = (const float*)&bv4[ni];
            #pragma unroll
            for (int r = 0; r < 4; ++r)
                xt[(base + n + r) * 1156 + pos] = acc[mi][ni][r] + bp[r];
        }
    }
}

// Wave-parallel scan + fused crop: one 32-lane group per chain.
// Border positions (h1/w1 in {0,33}) are synthesized as bias[c1] (never stored).
__global__ __launch_bounds__(256) void scan_emit_k(const float* __restrict__ xt,
                                                   const float* __restrict__ bias,
                                                   float* __restrict__ out) {
    const int grp = (blockIdx.x * 256 + threadIdx.x) >> 5;   // chain
    const int j   = threadIdx.x & 31;
    const int b   = grp / 768;
    const int c1  = grp - b * 768;
    const float* base = xt + (size_t)grp * 1156;
    float* outb = out + (size_t)b * 786432;                  // 3*512*512
    const int fl0 = c1 * 1156;
    const float bias_c = bias[c1];

    auto emit = [&](int fl, float v) {
        unsigned int c   = (fl >= 591872) ? 2u : (fl >= 295936 ? 1u : 0u);
        unsigned int rem = (unsigned int)fl - c * 295936u;
        unsigned int y   = rem / 544u;
        unsigned int xx  = rem - y * 544u;
        if (y >= 16u && y < 528u && xx >= 16u && xx < 528u)
            outb[(size_t)c * 262144 + (y - 16) * 512 + (xx - 16)] = v;
    };
    auto sel = [&](int p) -> float {                         // border -> bias
        float v = base[p];
        unsigned int h = (unsigned int)p / 34u;
        unsigned int w = (unsigned int)p - h * 34u;
        bool border = (h == 0u) | (h == 33u) | (w == 0u) | (w == 33u);
        return border ? bias_c : v;
    };

    // prefetch pipeline: rows i..i+3 live; load row i+4 each iter
    float r0 = bias_c;             // row 0 (pos 0..31) is entirely border
    float co = sel(32 + j);        // row 1
    float no = sel(64 + j);        // row 2
    float o2 = sel(96 + j);        // row 3
    float o3 = sel(128 + j);       // row 4
    emit(fl0 + j, r0);
    float pn = r0;
    float po_head = bias_c;

    for (int i = 1; i <= 30; ++i) {
        float ld = sel((i + 4) * 32 + j);           // row i+4 (max p=1119)
        float co_head = __shfl(co, 0, 32);          // orig[i*32]
        float no_head = __shfl(no, 0, 32);          // orig[(i+1)*32]
        float n2_head = __shfl(o2, 0, 32);          // orig[(i+2)*32]
        float UL = __shfl_up(pn, 1, 32);   if (j == 1)  UL = po_head;
        float U  = pn;
        float UR = __shfl_down(pn, 1, 32); if (j == 31) UR = co_head;
        float Rr = __shfl_down(co, 1, 32); if (j == 31) Rr = no_head;
        float D1 = __shfl_up(no, 1, 32);
        float D2 = no;
        float D3 = __shfl_down(no, 1, 32); if (j == 31) D3 = n2_head;
        float bv = (((UL + U) + (UR + Rr)) + ((D1 + D2) + D3)) * 0.125f;
        if (j == 1) bv += co_head * 0.125f;
        float t;
        t = __shfl_up(bv, 1, 32);  bv += (j > 1) ? 0.125f * t : 0.f;
        t = __shfl_up(bv, 2, 32);  bv += (j > 2) ? 0.015625f * t : 0.f;
        t = __shfl_up(bv, 4, 32);  bv += (j > 4) ? 2.44140625e-4f * t : 0.f;
        emit(fl0 + i * 32 + j, (j == 0) ? co : bv);
        pn = bv;
        po_head = co_head;
        co = no; no = o2; o2 = o3; o3 = ld;
    }
    // regs now: co=row31, no=row32, o2=row33, o3=row34 — originals/borders
    emit(fl0 +  992 + j, co);
    emit(fl0 + 1024 + j, no);
    emit(fl0 + 1056 + j, o2);
    emit(fl0 + 1088 + j, o3);
    emit(fl0 + 1120 + j, sel(1120 + j));
    if (j < 4) emit(fl0 + 1152 + j, bias_c);        // p=1152..1155: h1=33 border
}

extern "C" void kernel_launch(void* const* d_in, const int* in_sizes, int n_in,
                              void* d_out, int out_size, void* d_ws, size_t ws_size,
                              hipStream_t stream) {
    const float* x    = (const float*)d_in[0];
    const float* w    = (const float*)d_in[1];
    const float* bias = (const float*)d_in[2];
    float* out = (float*)d_out;
    float* xt  = (float*)d_ws;   // 12288*1156 fp32 = 56.8 MB

    unsigned short* a_bf = (unsigned short*)d_out;          // 25.2 MB
    unsigned short* w_bf = a_bf + (size_t)16384 * 768;      // +1.18 MB

    prep_k<<<6432, 256, 0, stream>>>(x, w, a_bf, w_bf);
    conv_gemm_mfma_k<<<dim3(128, 6), 256, 0, stream>>>(a_bf, w_bf, bias, xt);
    scan_emit_k<<<1536, 256, 0, stream>>>(xt, bias, out);
}

// Round 7
// 97.407 us; speedup vs baseline: 1.0262x; 1.0262x over previous
//
#include <hip/hip_runtime.h>
#include <hip/hip_bf16.h>

// Pipeline (chain = b*768 + c1, 12288 chains):
//  d_ws  : xt [12288][1024] bf16 (interior 32x32 conv outputs ONLY) = 25.2 MB.
//          Border positions of the 34x34 grid are never materialized; the scan
//          synthesizes bias[c1] for them.
//  d_out : scratch for bf16 A ([16384][768]) + bf16 W ([768][768]) during GEMM,
//          then fully overwritten with the final cropped output by scan_emit_k.
//  1) prep_k         : convert x and w to bf16
//  2) conv_gemm_mfma : 128x128 MFMA bf16 GEMM, 2-phase LDS dbuf, (row>>1)&3
//                      chunk-XOR LDS swizzle (8-way -> 2-way bank conflicts),
//                      packed ushort4 bf16 epilogue (full-line writes, no RMW)
//  3) scan_emit_k    : wave-parallel recurrence, TWO chains per 32-lane group
//                      (2x ILP on the serial chain), 4-row register prefetch,
//                      border synthesis, fused crop emit (fp32 out).

typedef __attribute__((ext_vector_type(8))) short s8v;     // 8 bf16
typedef __attribute__((ext_vector_type(4))) float f4v;     // MFMA acc
typedef __attribute__((ext_vector_type(8))) unsigned short us8;
typedef __attribute__((ext_vector_type(4))) unsigned short us4;

__device__ __forceinline__ unsigned short f2bf(float f) {
    __hip_bfloat16 h = __float2bfloat16(f);
    return *reinterpret_cast<unsigned short*>(&h);
}
__device__ __forceinline__ float bf2f(unsigned short u) {
    unsigned int v = (unsigned int)u << 16;
    union { unsigned int i; float f; } c; c.i = v; return c.f;
}

__device__ __forceinline__ void gload_lds16(const void* g, void* l) {
    __builtin_amdgcn_global_load_lds(
        (const __attribute__((address_space(1))) unsigned int*)g,
        (__attribute__((address_space(3))) unsigned int*)l,
        16, 0, 0);
}

// block ranges: [0,6144) convert_x, [6144,6432) convert_w
__global__ __launch_bounds__(256) void prep_k(const float* __restrict__ x,
                                              const float* __restrict__ w,
                                              unsigned short* __restrict__ a_bf,
                                              unsigned short* __restrict__ w_bf) {
    const int bid = blockIdx.x;
    if (bid < 6144) {
        // x [16][3][512][512] f32 -> A_bf [16384][768] bf16, m=(b,ph,pw), k=(c,py,px)
        int g = bid * 256 + threadIdx.x;
        int f = g << 3;
        int wc = f & 511;
        int h  = (f >> 9) & 511;
        int cb = f >> 18;
        int c  = cb % 3, b = cb / 3;
        const float4 v0 = *(const float4*)(x + f);
        const float4 v1 = *(const float4*)(x + f + 4);
        int m = (b << 10) + ((h >> 4) << 5) + (wc >> 4);
        int k = (c << 8) + ((h & 15) << 4) + (wc & 15);
        us8 o;
        o[0] = f2bf(v0.x); o[1] = f2bf(v0.y); o[2] = f2bf(v0.z); o[3] = f2bf(v0.w);
        o[4] = f2bf(v1.x); o[5] = f2bf(v1.y); o[6] = f2bf(v1.z); o[7] = f2bf(v1.w);
        *(us8*)(a_bf + (size_t)m * 768 + k) = o;
    } else {
        int g = (bid - 6144) * 256 + threadIdx.x;
        int f = g << 3;
        const float4 v0 = *(const float4*)(w + f);
        const float4 v1 = *(const float4*)(w + f + 4);
        us8 u;
        u[0] = f2bf(v0.x); u[1] = f2bf(v0.y); u[2] = f2bf(v0.z); u[3] = f2bf(v0.w);
        u[4] = f2bf(v1.x); u[5] = f2bf(v1.y); u[6] = f2bf(v1.z); u[7] = f2bf(v1.w);
        *(us8*)(w_bf + f) = u;
    }
}

// C[m][n] = sum_k A[m][k] * W[n][k]; 128x128 tile, BK=32, 4 waves, 2-phase dbuf.
// LDS swizzle: LDS(row, chunk) holds global chunk (chunk ^ ((row>>1)&3));
// applied on the global SOURCE address (stage) and the ds_read address (read).
__global__ __launch_bounds__(256) void conv_gemm_mfma_k(const unsigned short* __restrict__ A,
                                                        const unsigned short* __restrict__ W,
                                                        const float* __restrict__ bias,
                                                        unsigned short* __restrict__ xt) {
    __shared__ __align__(16) unsigned short As[2][128 * 32];
    __shared__ __align__(16) unsigned short Bs[2][128 * 32];
    const int tid  = threadIdx.x;
    const int lane = tid & 63, wv = tid >> 6;
    const int wr = wv >> 1, wc = wv & 1;
    const int m0 = blockIdx.x << 7, n0 = blockIdx.y << 7;

    f4v acc[4][4] = {};

    const int l2 = lane >> 2;
    const int kx = ((lane & 3) ^ ((l2 >> 1) & 3)) << 3;   // inverse-swizzled source
    const unsigned short* gA = A + (size_t)(m0 + (wv << 5) + l2) * 768 + kx;
    const unsigned short* gB = W + (size_t)(n0 + (wv << 5) + l2) * 768 + kx;

    auto stage = [&](int buf, int k0) {
        gload_lds16(gA + k0,            As[buf] + (wv << 10));
        gload_lds16(gA + k0 + 16 * 768, As[buf] + (wv << 10) + 512);
        gload_lds16(gB + k0,            Bs[buf] + (wv << 10));
        gload_lds16(gB + k0 + 16 * 768, Bs[buf] + (wv << 10) + 512);
    };

    stage(0, 0);
    asm volatile("s_waitcnt vmcnt(0)" ::: "memory");
    __syncthreads();

    const int cq = lane >> 4;
    int cur = 0;
    for (int t = 0; t < 24; ++t) {
        if (t < 23) stage(cur ^ 1, (t + 1) << 5);      // prefetch next K-tile
        s8v a[4], b[4];
        #pragma unroll
        for (int mi = 0; mi < 4; ++mi) {
            int ra = (wr << 6) + (mi << 4) + (lane & 15);
            a[mi] = *(const s8v*)(As[cur] + (ra << 5) + ((cq ^ ((ra >> 1) & 3)) << 3));
        }
        #pragma unroll
        for (int ni = 0; ni < 4; ++ni) {
            int rb = (wc << 6) + (ni << 4) + (lane & 15);
            b[ni] = *(const s8v*)(Bs[cur] + (rb << 5) + ((cq ^ ((rb >> 1) & 3)) << 3));
        }
        #pragma unroll
        for (int mi = 0; mi < 4; ++mi)
            #pragma unroll
            for (int ni = 0; ni < 4; ++ni)
                acc[mi][ni] = __builtin_amdgcn_mfma_f32_16x16x32_bf16(a[mi], b[ni], acc[mi][ni], 0, 0, 0);
        asm volatile("s_waitcnt vmcnt(0)" ::: "memory");
        __syncthreads();
        cur ^= 1;
    }

    // packed bf16 epilogue: lane owns 4 consecutive pw (r=0..3) at one n
    #pragma unroll
    for (int mi = 0; mi < 4; ++mi) {
        int m  = m0 + (wr << 6) + (mi << 4) + ((lane >> 4) << 2);
        int bb = m >> 10, ph = (m >> 5) & 31, pw = m & 31;
        unsigned short* dst = xt + (((size_t)bb * 768) << 10) + (ph << 5) + pw;
        #pragma unroll
        for (int ni = 0; ni < 4; ++ni) {
            int n = n0 + (wc << 6) + (ni << 4) + (lane & 15);
            float bv = bias[n];
            us4 o;
            o[0] = f2bf(acc[mi][ni][0] + bv);
            o[1] = f2bf(acc[mi][ni][1] + bv);
            o[2] = f2bf(acc[mi][ni][2] + bv);
            o[3] = f2bf(acc[mi][ni][3] + bv);
            *(us4*)(dst + ((size_t)n << 10)) = o;
        }
    }
}

// Wave-parallel scan + fused crop: one 32-lane group handles TWO chains.
// xt holds interior-only bf16; borders synthesized as bias[c1].
__global__ __launch_bounds__(256) void scan_emit_k(const unsigned short* __restrict__ xt,
                                                   const float* __restrict__ bias,
                                                   float* __restrict__ out) {
    const int grp = (blockIdx.x * 256 + threadIdx.x) >> 5;   // 0..6143
    const int j   = threadIdx.x & 31;
    const int ch0 = grp << 1;
    const int b   = ch0 / 768;          // ch0 even, 768 even -> ch0+1 same b
    const int cc0 = ch0 - b * 768;
    float* outb = out + (size_t)b * 786432;                  // 3*512*512

    const unsigned short* basep[2] = { xt + ((size_t)ch0 << 10),
                                       xt + ((size_t)(ch0 + 1) << 10) };
    const int   flb[2]   = { cc0 * 1156, (cc0 + 1) * 1156 };
    const float biasc[2] = { bias[cc0], bias[cc0 + 1] };

    auto emit = [&](int fl, float v) {
        unsigned int c   = (fl >= 591872) ? 2u : (fl >= 295936 ? 1u : 0u);
        unsigned int rem = (unsigned int)fl - c * 295936u;
        unsigned int y   = rem / 544u;
        unsigned int xx  = rem - y * 544u;
        if (y >= 16u && y < 528u && xx >= 16u && xx < 528u)
            outb[(size_t)c * 262144 + (y - 16) * 512 + (xx - 16)] = v;
    };
    auto sel = [&](int q, int p) -> float {     // p = flat index in 34x34 grid
        unsigned int h = (unsigned int)p / 34u;
        unsigned int w = (unsigned int)p - h * 34u;
        if ((h == 0u) | (h == 33u) | (w == 0u) | (w == 33u)) return biasc[q];
        return bf2f(basep[q][(h - 1u) * 32u + (w - 1u)]);
    };

    float pn[2], po_h[2], co[2], no[2], o2[2], o3[2];
    #pragma unroll
    for (int q = 0; q < 2; ++q) {
        co[q] = sel(q,  32 + j);
        no[q] = sel(q,  64 + j);
        o2[q] = sel(q,  96 + j);
        o3[q] = sel(q, 128 + j);
        emit(flb[q] + j, biasc[q]);             // flat row 0: all border
        pn[q]   = biasc[q];
        po_h[q] = biasc[q];
    }

    for (int i = 1; i <= 30; ++i) {
        float ld[2];
        #pragma unroll
        for (int q = 0; q < 2; ++q) ld[q] = sel(q, (i + 4) * 32 + j);
        #pragma unroll
        for (int q = 0; q < 2; ++q) {
            float co_head = __shfl(co[q], 0, 32);
            float no_head = __shfl(no[q], 0, 32);
            float n2_head = __shfl(o2[q], 0, 32);
            float UL = __shfl_up(pn[q], 1, 32);   if (j == 1)  UL = po_h[q];
            float U  = pn[q];
            float UR = __shfl_down(pn[q], 1, 32); if (j == 31) UR = co_head;
            float Rr = __shfl_down(co[q], 1, 32); if (j == 31) Rr = no_head;
            float D1 = __shfl_up(no[q], 1, 32);
            float D2 = no[q];
            float D3 = __shfl_down(no[q], 1, 32); if (j == 31) D3 = n2_head;
            float bv = (((UL + U) + (UR + Rr)) + ((D1 + D2) + D3)) * 0.125f;
            if (j == 1) bv += co_head * 0.125f;
            float t;
            t = __shfl_up(bv, 1, 32);  bv += (j > 1) ? 0.125f * t : 0.f;
            t = __shfl_up(bv, 2, 32);  bv += (j > 2) ? 0.015625f * t : 0.f;
            t = __shfl_up(bv, 4, 32);  bv += (j > 4) ? 2.44140625e-4f * t : 0.f;
            emit(flb[q] + i * 32 + j, (j == 0) ? co[q] : bv);
            pn[q]   = bv;
            po_h[q] = co_head;
            co[q] = no[q]; no[q] = o2[q]; o2[q] = o3[q]; o3[q] = ld[q];
        }
    }

    #pragma unroll
    for (int q = 0; q < 2; ++q) {
        emit(flb[q] +  992 + j, co[q]);         // rows 31..34: pass-through
        emit(flb[q] + 1024 + j, no[q]);
        emit(flb[q] + 1056 + j, o2[q]);
        emit(flb[q] + 1088 + j, o3[q]);
        emit(flb[q] + 1120 + j, sel(q, 1120 + j));
        if (j < 4) emit(flb[q] + 1152 + j, biasc[q]);   // h1=33 border tail
    }
}

extern "C" void kernel_launch(void* const* d_in, const int* in_sizes, int n_in,
                              void* d_out, int out_size, void* d_ws, size_t ws_size,
                              hipStream_t stream) {
    const float* x    = (const float*)d_in[0];
    const float* w    = (const float*)d_in[1];
    const float* bias = (const float*)d_in[2];
    float* out = (float*)d_out;
    unsigned short* xt = (unsigned short*)d_ws;   // 12288*1024 bf16 = 25.2 MB

    unsigned short* a_bf = (unsigned short*)d_out;          // 25.2 MB
    unsigned short* w_bf = a_bf + (size_t)16384 * 768;      // +1.18 MB

    prep_k<<<6432, 256, 0, stream>>>(x, w, a_bf, w_bf);
    conv_gemm_mfma_k<<<dim3(128, 6), 256, 0, stream>>>(a_bf, w_bf, bias, xt);
    scan_emit_k<<<768, 256, 0, stream>>>(xt, bias, out);
}

// Round 8
// 81.877 us; speedup vs baseline: 1.2208x; 1.1897x over previous
//
#include <hip/hip_runtime.h>
#include <hip/hip_bf16.h>

// Pipeline (chain = b*768 + c1, 12288 chains):
//  d_ws  : xt [12288][1024] bf16 (interior 32x32 conv outputs ONLY) = 25.2 MB.
//          Borders of the 34x34 grid are synthesized as bias[c1] in the scan.
//  d_out : scratch for bf16 W ([768][768], 1.18 MB) during GEMM, then fully
//          overwritten with the final cropped output by scan_emit_k.
//  1) prep_w_k       : w -> bf16
//  2) conv_gemm_fused: A-operand read DIRECTLY from x (fp32), converted in
//                      registers, ds_written to swizzled LDS; B via
//                      global_load_lds; 128x128 tile, 2-phase dbuf; packed
//                      bf16 us4 epilogue.
//  3) scan_emit_k    : wave-parallel recurrence, ONE chain per 32-lane group
//                      (6144 waves), 4-row register prefetch, 3-step
//                      Hillis-Steele, border synthesis, fused crop emit.

typedef __attribute__((ext_vector_type(8))) short s8v;     // 8 bf16
typedef __attribute__((ext_vector_type(4))) float f4v;     // MFMA acc
typedef __attribute__((ext_vector_type(8))) unsigned short us8;
typedef __attribute__((ext_vector_type(4))) unsigned short us4;

__device__ __forceinline__ unsigned short f2bf(float f) {
    __hip_bfloat16 h = __float2bfloat16(f);
    return *reinterpret_cast<unsigned short*>(&h);
}
__device__ __forceinline__ float bf2f(unsigned short u) {
    union { unsigned int i; float f; } c; c.i = (unsigned int)u << 16; return c.f;
}

__device__ __forceinline__ void gload_lds16(const void* g, void* l) {
    __builtin_amdgcn_global_load_lds(
        (const __attribute__((address_space(1))) unsigned int*)g,
        (__attribute__((address_space(3))) unsigned int*)l,
        16, 0, 0);
}

__global__ __launch_bounds__(256) void prep_w_k(const float* __restrict__ w,
                                                unsigned short* __restrict__ w_bf) {
    int g = blockIdx.x * 256 + threadIdx.x;    // 73728 threads, 8 floats each
    int f = g << 3;
    const float4 v0 = *(const float4*)(w + f);
    const float4 v1 = *(const float4*)(w + f + 4);
    us8 u;
    u[0] = f2bf(v0.x); u[1] = f2bf(v0.y); u[2] = f2bf(v0.z); u[3] = f2bf(v0.w);
    u[4] = f2bf(v1.x); u[5] = f2bf(v1.y); u[6] = f2bf(v1.z); u[7] = f2bf(v1.w);
    *(us8*)(w_bf + f) = u;
}

// C[m][n] = sum_k A[m][k]*W[n][k]; m=(b,ph,pw), k=(c,py,px), n=c1.
// A k-tile (BK=32: one c, py pair) for the 128-m tile = 8 contiguous rows of
// x[b][c] -> loaded fp32, converted, ds_written with the (row>>1)&3 chunk-XOR
// swizzle. B staged via global_load_lds with inverse-swizzled source address.
__global__ __launch_bounds__(256) void conv_gemm_fused_k(const float* __restrict__ x,
                                                         const unsigned short* __restrict__ W,
                                                         const float* __restrict__ bias,
                                                         unsigned short* __restrict__ xt) {
    __shared__ __align__(16) unsigned short As[2][128 * 32];
    __shared__ __align__(16) unsigned short Bs[2][128 * 32];
    const int tid  = threadIdx.x;
    const int lane = tid & 63, wv = tid >> 6;
    const int wr = wv >> 1, wc = wv & 1;
    const int m0 = blockIdx.x << 7, n0 = blockIdx.y << 7;

    f4v acc[4][4] = {};

    // ---- A staging (registers) ----
    const int bb  = m0 >> 10;
    const int ph0 = (m0 >> 5) & 31;                 // multiple of 4
    const int h_l = tid >> 5, pw = tid & 31;        // 8 h-rows x 32 pw chunks
    const int ph_l = h_l >> 1, py_l = h_l & 1;
    const int arow = (ph_l << 5) + pw;              // LDS row 0..127
    const int axr  = (arow >> 1) & 3;
    const int aoff0 = arow * 32 + ((( py_l << 1)      ^ axr) << 3);  // elems
    const int aoff1 = arow * 32 + ((((py_l << 1) | 1) ^ axr) << 3);
    const float* asrc = x + (size_t)bb * 786432
                          + ((ph0 + ph_l) * 16 + py_l) * 512 + (pw << 4);
    float4 ar0, ar1, ar2, ar3;
    auto loadA = [&](int k0) {
        const float* s = asrc + (k0 >> 8) * 262144 + ((k0 >> 4) & 15) * 512;
        ar0 = *(const float4*)(s);      ar1 = *(const float4*)(s + 4);
        ar2 = *(const float4*)(s + 8);  ar3 = *(const float4*)(s + 12);
    };
    auto writeA = [&](int buf) {
        us8 lo, hi;
        lo[0]=f2bf(ar0.x); lo[1]=f2bf(ar0.y); lo[2]=f2bf(ar0.z); lo[3]=f2bf(ar0.w);
        lo[4]=f2bf(ar1.x); lo[5]=f2bf(ar1.y); lo[6]=f2bf(ar1.z); lo[7]=f2bf(ar1.w);
        hi[0]=f2bf(ar2.x); hi[1]=f2bf(ar2.y); hi[2]=f2bf(ar2.z); hi[3]=f2bf(ar2.w);
        hi[4]=f2bf(ar3.x); hi[5]=f2bf(ar3.y); hi[6]=f2bf(ar3.z); hi[7]=f2bf(ar3.w);
        *(us8*)(As[buf] + aoff0) = lo;
        *(us8*)(As[buf] + aoff1) = hi;
    };

    // ---- B staging (global_load_lds, inverse-swizzled source) ----
    const int l2 = lane >> 2;
    const int kx = ((lane & 3) ^ ((l2 >> 1) & 3)) << 3;
    const unsigned short* gB = W + (size_t)(n0 + (wv << 5) + l2) * 768 + kx;
    auto stageB = [&](int buf, int k0) {
        gload_lds16(gB + k0,            Bs[buf] + (wv << 10));
        gload_lds16(gB + k0 + 16 * 768, Bs[buf] + (wv << 10) + 512);
    };

    stageB(0, 0);
    loadA(0);
    writeA(0);                   // compiler inserts waits for the fp32 loads
    __syncthreads();             // drains B gload_lds (vmcnt) + A ds_writes

    const int cq = lane >> 4;
    int cur = 0;
    for (int t = 0; t < 24; ++t) {
        if (t < 23) { stageB(cur ^ 1, (t + 1) << 5); loadA((t + 1) << 5); }
        s8v a[4], b[4];
        #pragma unroll
        for (int mi = 0; mi < 4; ++mi) {
            int ra = (wr << 6) + (mi << 4) + (lane & 15);
            a[mi] = *(const s8v*)(As[cur] + (ra << 5) + ((cq ^ ((ra >> 1) & 3)) << 3));
        }
        #pragma unroll
        for (int ni = 0; ni < 4; ++ni) {
            int rb = (wc << 6) + (ni << 4) + (lane & 15);
            b[ni] = *(const s8v*)(Bs[cur] + (rb << 5) + ((cq ^ ((rb >> 1) & 3)) << 3));
        }
        #pragma unroll
        for (int mi = 0; mi < 4; ++mi)
            #pragma unroll
            for (int ni = 0; ni < 4; ++ni)
                acc[mi][ni] = __builtin_amdgcn_mfma_f32_16x16x32_bf16(a[mi], b[ni], acc[mi][ni], 0, 0, 0);
        if (t < 23) writeA(cur ^ 1);
        __syncthreads();         // barrier drain covers gload_lds + ds_writes
        cur ^= 1;
    }

    // packed bf16 epilogue: lane owns 4 consecutive pw (acc regs) at one n
    #pragma unroll
    for (int mi = 0; mi < 4; ++mi) {
        int m  = m0 + (wr << 6) + (mi << 4) + ((lane >> 4) << 2);
        int ph = (m >> 5) & 31, pwm = m & 31;
        unsigned short* dst = xt + (((size_t)bb * 768) << 10) + (ph << 5) + pwm;
        #pragma unroll
        for (int ni = 0; ni < 4; ++ni) {
            int n = n0 + (wc << 6) + (ni << 4) + (lane & 15);
            float bv = bias[n];
            us4 o;
            o[0] = f2bf(acc[mi][ni][0] + bv);
            o[1] = f2bf(acc[mi][ni][1] + bv);
            o[2] = f2bf(acc[mi][ni][2] + bv);
            o[3] = f2bf(acc[mi][ni][3] + bv);
            *(us4*)(dst + ((size_t)n << 10)) = o;
        }
    }
}

// Wave-parallel scan + fused crop: ONE chain per 32-lane group (12288 groups).
__global__ __launch_bounds__(256) void scan_emit_k(const unsigned short* __restrict__ xt,
                                                   const float* __restrict__ bias,
                                                   float* __restrict__ out) {
    const int grp = (blockIdx.x * 256 + threadIdx.x) >> 5;   // chain 0..12287
    const int j   = threadIdx.x & 31;
    const int b   = grp / 768;
    const int c1  = grp - b * 768;
    const unsigned short* basep = xt + ((size_t)grp << 10);
    float* outb = out + (size_t)b * 786432;                  // 3*512*512
    const int fl0 = c1 * 1156;
    const float bias_c = bias[c1];

    auto emit = [&](int fl, float v) {
        unsigned int c   = (fl >= 591872) ? 2u : (fl >= 295936 ? 1u : 0u);
        unsigned int rem = (unsigned int)fl - c * 295936u;
        unsigned int y   = rem / 544u;
        unsigned int xx  = rem - y * 544u;
        if (y >= 16u && y < 528u && xx >= 16u && xx < 528u)
            outb[(size_t)c * 262144 + (y - 16) * 512 + (xx - 16)] = v;
    };
    auto sel = [&](int p) -> float {            // flat 34x34 index -> value
        unsigned int h = (unsigned int)p / 34u;
        unsigned int w = (unsigned int)p - h * 34u;
        if ((h == 0u) | (h == 33u) | (w == 0u) | (w == 33u)) return bias_c;
        return bf2f(basep[(h - 1u) * 32u + (w - 1u)]);
    };

    float co = sel( 32 + j);       // row 1
    float no = sel( 64 + j);       // row 2
    float o2 = sel( 96 + j);       // row 3
    float o3 = sel(128 + j);       // row 4
    emit(fl0 + j, bias_c);         // flat row 0: entirely border
    float pn   = bias_c;
    float po_h = bias_c;

    for (int i = 1; i <= 30; ++i) {
        float ld = sel((i + 4) * 32 + j);           // row i+4 (max p=1119)
        float co_head = __shfl(co, 0, 32);
        float no_head = __shfl(no, 0, 32);
        float n2_head = __shfl(o2, 0, 32);
        float UL = __shfl_up(pn, 1, 32);   if (j == 1)  UL = po_h;
        float U  = pn;
        float UR = __shfl_down(pn, 1, 32); if (j == 31) UR = co_head;
        float Rr = __shfl_down(co, 1, 32); if (j == 31) Rr = no_head;
        float D1 = __shfl_up(no, 1, 32);
        float D2 = no;
        float D3 = __shfl_down(no, 1, 32); if (j == 31) D3 = n2_head;
        float bv = (((UL + U) + (UR + Rr)) + ((D1 + D2) + D3)) * 0.125f;
        if (j == 1) bv += co_head * 0.125f;
        float t;
        t = __shfl_up(bv, 1, 32);  bv += (j > 1) ? 0.125f * t : 0.f;
        t = __shfl_up(bv, 2, 32);  bv += (j > 2) ? 0.015625f * t : 0.f;
        t = __shfl_up(bv, 4, 32);  bv += (j > 4) ? 2.44140625e-4f * t : 0.f;
        emit(fl0 + i * 32 + j, (j == 0) ? co : bv);
        pn   = bv;
        po_h = co_head;
        co = no; no = o2; o2 = o3; o3 = ld;
    }
    // regs now: co=row31, no=row32, o2=row33, o3=row34 — originals/borders
    emit(fl0 +  992 + j, co);
    emit(fl0 + 1024 + j, no);
    emit(fl0 + 1056 + j, o2);
    emit(fl0 + 1088 + j, o3);
    emit(fl0 + 1120 + j, sel(1120 + j));
    if (j < 4) emit(fl0 + 1152 + j, bias_c);    // p=1152..1155: h1=33 border
}

extern "C" void kernel_launch(void* const* d_in, const int* in_sizes, int n_in,
                              void* d_out, int out_size, void* d_ws, size_t ws_size,
                              hipStream_t stream) {
    const float* x    = (const float*)d_in[0];
    const float* w    = (const float*)d_in[1];
    const float* bias = (const float*)d_in[2];
    float* out = (float*)d_out;
    unsigned short* xt = (unsigned short*)d_ws;   // 12288*1024 bf16 = 25.2 MB

    unsigned short* w_bf = (unsigned short*)d_out;   // 1.18 MB scratch in d_out

    prep_w_k<<<288, 256, 0, stream>>>(w, w_bf);
    conv_gemm_fused_k<<<dim3(128, 6), 256, 0, stream>>>(x, w_bf, bias, xt);
    scan_emit_k<<<1536, 256, 0, stream>>>(xt, bias, out);
}